// Round 5
// baseline (357.914 us; speedup 1.0000x reference)
//
#include <hip/hip_runtime.h>
#include <hip/hip_cooperative_groups.h>

namespace cg = cooperative_groups;

#define FDIM 128
#define NBMAX 512   // coarse buckets (dst>>8); supports n <= 131072
#define EPB 4096    // edges per chunk in hist/scatter phases
#define CPAD 16     // counter padding: one counter per 64-B line
#define NBLK 512    // cooperative grid: 2 blocks/CU guaranteed co-resident (LDS allows 4)
#define B1 6        // gemm tiles per gemm-block during scatter phase (bounded so sync2 isn't delayed)

typedef __attribute__((ext_vector_type(8))) short bf16x8;
typedef __attribute__((ext_vector_type(4))) float f32x4;

__device__ __forceinline__ unsigned short f2bf(float f) {
    unsigned int u = __float_as_uint(f);
    unsigned int r = u + 0x7fffu + ((u >> 16) & 1u);  // RNE
    return (unsigned short)(r >> 16);
}

// ---- one 64-row GEMM tile: hs[row, :] = bf16(x[row, :] @ W), split hi/lo bf16 A ----
__device__ __forceinline__ void gemm_tile(int tt, const float* __restrict__ x,
                                          const unsigned short* Bs,
                                          unsigned short* __restrict__ hs, int n, int tid) {
    const int lane = tid & 63;
    const int wid = tid >> 6;
    const int m = lane & 15;
    const int quad = lane >> 4;
    const int row0 = tt * 64 + wid * 16;

    int rowA = row0 + m;
    if (rowA >= n) rowA = n - 1;
    const float* xr = x + (size_t)rowA * FDIM;

    f32x4 acc[8];
    #pragma unroll
    for (int ct = 0; ct < 8; ++ct) acc[ct] = (f32x4){0.f, 0.f, 0.f, 0.f};

    #pragma unroll
    for (int kc = 0; kc < 4; ++kc) {
        const int kb = kc * 32 + quad * 8;
        float4 xa = *(const float4*)(xr + kb);
        float4 xb = *(const float4*)(xr + kb + 4);
        float v[8] = {xa.x, xa.y, xa.z, xa.w, xb.x, xb.y, xb.z, xb.w};
        bf16x8 ahi, alo;
        #pragma unroll
        for (int j = 0; j < 8; ++j) {
            unsigned short hh = f2bf(v[j]);
            ahi[j] = (short)hh;
            alo[j] = (short)f2bf(v[j] - __uint_as_float(((unsigned)hh) << 16));
        }
        const int g = kc * 4 + quad;
        #pragma unroll
        for (int ct = 0; ct < 8; ++ct) {
            int nidx = ct * 16 + m;
            const bf16x8 bhi = *(const bf16x8*)(Bs + (size_t)nidx * FDIM + (g ^ m) * 8);
            acc[ct] = __builtin_amdgcn_mfma_f32_16x16x32_bf16(ahi, bhi, acc[ct], 0, 0, 0);
            acc[ct] = __builtin_amdgcn_mfma_f32_16x16x32_bf16(alo, bhi, acc[ct], 0, 0, 0);
        }
    }

    #pragma unroll
    for (int r = 0; r < 4; ++r) {
        int row = row0 + quad * 4 + r;
        if (row >= n) continue;
        unsigned short* hrow = hs + (size_t)row * FDIM;
        #pragma unroll
        for (int ct = 0; ct < 8; ++ct) hrow[ct * 16 + m] = f2bf(acc[ct][r]);
    }
}

__device__ __forceinline__ void stage_Bs(const unsigned short* __restrict__ whi,
                                         unsigned short* Bs, int tid) {
    // stage whi with XOR swizzle on 16B granules: g -> g^(nn&15)
    const float4* g4 = (const float4*)whi;
    float4* l4 = (float4*)Bs;
    for (int i = tid; i < 2048; i += 256) {
        int nn = i >> 4;
        int g = i & 15;
        l4[nn * 16 + (g ^ (nn & 15))] = g4[i];
    }
}

// ================= fused pre-gather pipeline (cooperative) =================
// Phase A: coarse histogram (bcnt, padded) + W->bf16 transpose (whi)
//   grid.sync()
// Phase C: blocks < nchunks: LDS counting-sort scatter -> coarse (bucket-contiguous)
//          other blocks:     up to B1 gemm tiles via global ticket
//   grid.sync()
// Phase D: blocks < nb: per-bucket finalize (dinv/row_start/ebuf); then ALL blocks
//          drain remaining gemm tiles via ticket. Kernel end = everything done.
__global__ __launch_bounds__(256, 2) void k_fused(
    const int* __restrict__ src, const int* __restrict__ dst,
    int* __restrict__ bcnt, int* __restrict__ gcur, int* __restrict__ gtick,
    unsigned int* __restrict__ coarse,
    const float* __restrict__ x, const float* __restrict__ W,
    unsigned short* __restrict__ whi, unsigned short* __restrict__ hs,
    float* __restrict__ dinv, int* __restrict__ row_start, int* __restrict__ ebuf,
    int e, int n, int nchunks, int nb, int ntiles) {
    union ShU {
        unsigned short Bs[FDIM * FDIM];            // 32 KB (gemm)
        struct {
            int sval[EPB];                         // 16 KB sorted values
            unsigned short sbkt[EPB];              // 8 KB bucket ids
            int loff[NBMAX];                       // 2 KB local excl offsets
            int gbs[NBMAX];                        // 2 KB global chunk bases
        } sc;                                      // 28 KB (scatter)
        struct { int ld[256]; int pf[256]; int pos[256]; } bf;  // 3 KB (bfin)
    };
    __shared__ ShU S;
    __shared__ int cur[NBMAX];      // 2 KB
    __shared__ int bb[NBMAX + 1];   // 2 KB, persists C->D
    __shared__ int tkt;

    const int bid = (int)blockIdx.x;
    const int tid = (int)threadIdx.x;
    cg::grid_group grid = cg::this_grid();

    // ---------------- Phase A ----------------
    for (int c = bid; c < nchunks; c += NBLK) {
        cur[tid] = 0;
        cur[tid + 256] = 0;
        __syncthreads();
        int base = c * EPB, end2 = min(base + EPB, e);
        for (int i = base + tid; i < end2; i += 256) atomicAdd(&cur[dst[i] >> 8], 1);
        __syncthreads();
        for (int i = tid; i < NBMAX; i += 256) {
            int cc = cur[i];
            if (cc) atomicAdd(&bcnt[i * CPAD], cc);
        }
        __syncthreads();
    }
    for (int id = bid * 256 + tid; id < FDIM * FDIM; id += NBLK * 256) {
        int k = id >> 7, nn = id & 127;
        whi[nn * FDIM + k] = f2bf(W[id]);  // W[k][nn] -> whi[nn][k]
    }

    grid.sync();

    // ---------------- bb: exclusive bucket bases (all blocks, redundant) ----------------
    {
        int* scr = S.sc.sval;
        int v0 = bcnt[tid * CPAD], v1 = bcnt[(tid + 256) * CPAD];
        scr[tid] = v0;
        scr[tid + 256] = v1;
        __syncthreads();
        for (int off = 1; off < NBMAX; off <<= 1) {
            int a0 = (tid >= off) ? scr[tid - off] : 0;
            int a1 = (tid + 256 >= off) ? scr[tid + 256 - off] : 0;
            __syncthreads();
            scr[tid] += a0;
            scr[tid + 256] += a1;
            __syncthreads();
        }
        bb[tid] = scr[tid] - v0;
        bb[tid + 256] = scr[tid + 256] - v1;
        if (tid == 0) bb[NBMAX] = e;
        __syncthreads();
    }

    bool staged = false;

    // ---------------- Phase C ----------------
    if (bid < nchunks) {
        for (int c = bid; c < nchunks; c += NBLK) {
            int* scr = S.sc.sval;
            cur[tid] = 0;
            cur[tid + 256] = 0;
            __syncthreads();
            int base = c * EPB, end2 = min(base + EPB, e), cnt = end2 - base;
            for (int i = base + tid; i < end2; i += 256) atomicAdd(&cur[dst[i] >> 8], 1);
            __syncthreads();
            int c0 = cur[tid], c1 = cur[tid + 256];
            scr[tid] = c0;
            scr[tid + 256] = c1;
            __syncthreads();
            for (int off = 1; off < NBMAX; off <<= 1) {
                int a0 = (tid >= off) ? scr[tid - off] : 0;
                int a1 = (tid + 256 >= off) ? scr[tid + 256 - off] : 0;
                __syncthreads();
                scr[tid] += a0;
                scr[tid + 256] += a1;
                __syncthreads();
            }
            S.sc.loff[tid] = scr[tid] - c0;
            S.sc.loff[tid + 256] = scr[tid + 256] - c1;
            S.sc.gbs[tid] = bb[tid] + (c0 ? atomicAdd(&gcur[tid * CPAD], c0) : 0);
            S.sc.gbs[tid + 256] = bb[tid + 256] + (c1 ? atomicAdd(&gcur[(tid + 256) * CPAD], c1) : 0);
            cur[tid] = 0;
            cur[tid + 256] = 0;
            __syncthreads();
            for (int i = base + tid; i < end2; i += 256) {
                int d = dst[i];
                int b = d >> 8;
                int lp = atomicAdd(&cur[b], 1);
                int p2 = S.sc.loff[b] + lp;
                S.sc.sval[p2] = (int)(((unsigned)src[i] << 8) | (unsigned)(d & 255));
                S.sc.sbkt[p2] = (unsigned short)b;
            }
            __syncthreads();
            for (int s2 = tid; s2 < cnt; s2 += 256) {
                int b = S.sc.sbkt[s2];
                coarse[S.sc.gbs[b] + (s2 - S.sc.loff[b])] = (unsigned)S.sc.sval[s2];
            }
            __syncthreads();
        }
    } else {
        for (int k = 0; k < B1; ++k) {
            __syncthreads();
            if (tid == 0) tkt = atomicAdd(gtick, 1);
            __syncthreads();
            int t = tkt;
            if (t >= ntiles) break;
            if (!staged) {
                stage_Bs(whi, S.Bs, tid);
                staged = true;
                __syncthreads();
            }
            gemm_tile(t, x, S.Bs, hs, n, tid);
        }
    }

    grid.sync();

    // ---------------- Phase D: bfin, then drain gemm ----------------
    for (int b2 = bid; b2 < nb; b2 += NBLK) {
        int s = bb[b2], t = bb[b2 + 1];
        __syncthreads();  // prior union use done
        S.bf.ld[tid] = 0;
        __syncthreads();
        for (int i = s + tid; i < t; i += 256) atomicAdd(&S.bf.ld[coarse[i] & 255u], 1);
        __syncthreads();
        int v = S.bf.ld[tid];  // deg-1 of this node
        S.bf.pf[tid] = v;
        __syncthreads();
        for (int off = 1; off < 256; off <<= 1) {
            int tv = (tid >= off) ? S.bf.pf[tid - off] : 0;
            __syncthreads();
            S.bf.pf[tid] += tv;
            __syncthreads();
        }
        int rs = s + S.bf.pf[tid] - v;
        S.bf.pos[tid] = rs;
        int node = b2 * 256 + tid;
        if (node < n) {
            dinv[node] = rsqrtf((float)(v + 1));
            row_start[node] = rs;
        }
        __syncthreads();
        for (int i = s + tid; i < t; i += 256) {
            unsigned int p = coarse[i];
            int pp = atomicAdd(&S.bf.pos[p & 255u], 1);
            ebuf[pp] = (int)(p >> 8);
        }
        __syncthreads();
    }
    if (bid == 0 && tid == 0) row_start[n] = e;  // sentinel for gather

    while (true) {
        __syncthreads();
        if (tid == 0) tkt = atomicAdd(gtick, 1);
        __syncthreads();
        int t = tkt;
        if (t >= ntiles) break;
        if (!staged) {
            stage_Bs(whi, S.Bs, tid);
            staged = true;
            __syncthreads();
        }
        gemm_tile(t, x, S.Bs, hs, n, tid);
    }
}

// ---------------- gather: out[i] = dinv[i]*(dinv[i]*h[i] + sum dinv[s]*h[s]) + b ----------------
// persistent grid-stride waves (node per wave), 8-edge unrolled + software-pipelined
// ebuf index loads. Bias hoisted out of the node loop.
__global__ __launch_bounds__(256, 8) void k_gather(
    const unsigned short* __restrict__ hs, const int* __restrict__ ebuf,
    const int* __restrict__ row_start, const float* __restrict__ dinv,
    const float* __restrict__ bias, float* __restrict__ out, int n) {
    const int lane = threadIdx.x & 63;
    const int gw = (int)blockIdx.x * 4 + (threadIdx.x >> 6);
    const int nw = (int)gridDim.x * 4;

    const unsigned int* __restrict__ hl = (const unsigned int*)hs + lane;
    const float2 bb = ((const float2*)bias)[lane];

    for (int i = gw; i < n; i += nw) {
        int beg = row_start[i];
        int end = row_start[i + 1];
        float di = dinv[i];

        unsigned int u = hl[(unsigned)i << 6];
        float ax = di * __uint_as_float(u << 16);
        float ay = di * __uint_as_float(u & 0xffff0000u);
        float bx = 0.f, by = 0.f;

        int j = beg;
        int stop8 = j + ((end - j) & ~7);
        if (j < stop8) {
            int s0 = ebuf[j + 0], s1 = ebuf[j + 1], s2 = ebuf[j + 2], s3 = ebuf[j + 3];
            int s4 = ebuf[j + 4], s5 = ebuf[j + 5], s6 = ebuf[j + 6], s7 = ebuf[j + 7];
            j += 8;
            while (j < stop8) {
                unsigned int u0 = hl[(unsigned)s0 << 6], u1 = hl[(unsigned)s1 << 6];
                unsigned int u2 = hl[(unsigned)s2 << 6], u3 = hl[(unsigned)s3 << 6];
                unsigned int u4 = hl[(unsigned)s4 << 6], u5 = hl[(unsigned)s5 << 6];
                unsigned int u6 = hl[(unsigned)s6 << 6], u7 = hl[(unsigned)s7 << 6];
                float d0 = dinv[s0], d1 = dinv[s1], d2 = dinv[s2], d3 = dinv[s3];
                float d4 = dinv[s4], d5 = dinv[s5], d6 = dinv[s6], d7 = dinv[s7];
                int t0 = ebuf[j + 0], t1 = ebuf[j + 1], t2 = ebuf[j + 2], t3 = ebuf[j + 3];
                int t4 = ebuf[j + 4], t5 = ebuf[j + 5], t6 = ebuf[j + 6], t7 = ebuf[j + 7];
                ax = fmaf(d0, __uint_as_float(u0 << 16), ax);
                ay = fmaf(d0, __uint_as_float(u0 & 0xffff0000u), ay);
                bx = fmaf(d1, __uint_as_float(u1 << 16), bx);
                by = fmaf(d1, __uint_as_float(u1 & 0xffff0000u), by);
                ax = fmaf(d2, __uint_as_float(u2 << 16), ax);
                ay = fmaf(d2, __uint_as_float(u2 & 0xffff0000u), ay);
                bx = fmaf(d3, __uint_as_float(u3 << 16), bx);
                by = fmaf(d3, __uint_as_float(u3 & 0xffff0000u), by);
                ax = fmaf(d4, __uint_as_float(u4 << 16), ax);
                ay = fmaf(d4, __uint_as_float(u4 & 0xffff0000u), ay);
                bx = fmaf(d5, __uint_as_float(u5 << 16), bx);
                by = fmaf(d5, __uint_as_float(u5 & 0xffff0000u), by);
                ax = fmaf(d6, __uint_as_float(u6 << 16), ax);
                ay = fmaf(d6, __uint_as_float(u6 & 0xffff0000u), ay);
                bx = fmaf(d7, __uint_as_float(u7 << 16), bx);
                by = fmaf(d7, __uint_as_float(u7 & 0xffff0000u), by);
                s0 = t0; s1 = t1; s2 = t2; s3 = t3;
                s4 = t4; s5 = t5; s6 = t6; s7 = t7;
                j += 8;
            }
            {
                unsigned int u0 = hl[(unsigned)s0 << 6], u1 = hl[(unsigned)s1 << 6];
                unsigned int u2 = hl[(unsigned)s2 << 6], u3 = hl[(unsigned)s3 << 6];
                unsigned int u4 = hl[(unsigned)s4 << 6], u5 = hl[(unsigned)s5 << 6];
                unsigned int u6 = hl[(unsigned)s6 << 6], u7 = hl[(unsigned)s7 << 6];
                float d0 = dinv[s0], d1 = dinv[s1], d2 = dinv[s2], d3 = dinv[s3];
                float d4 = dinv[s4], d5 = dinv[s5], d6 = dinv[s6], d7 = dinv[s7];
                ax = fmaf(d0, __uint_as_float(u0 << 16), ax);
                ay = fmaf(d0, __uint_as_float(u0 & 0xffff0000u), ay);
                bx = fmaf(d1, __uint_as_float(u1 << 16), bx);
                by = fmaf(d1, __uint_as_float(u1 & 0xffff0000u), by);
                ax = fmaf(d2, __uint_as_float(u2 << 16), ax);
                ay = fmaf(d2, __uint_as_float(u2 & 0xffff0000u), ay);
                bx = fmaf(d3, __uint_as_float(u3 << 16), bx);
                by = fmaf(d3, __uint_as_float(u3 & 0xffff0000u), by);
                ax = fmaf(d4, __uint_as_float(u4 << 16), ax);
                ay = fmaf(d4, __uint_as_float(u4 & 0xffff0000u), ay);
                bx = fmaf(d5, __uint_as_float(u5 << 16), bx);
                by = fmaf(d5, __uint_as_float(u5 & 0xffff0000u), by);
                ax = fmaf(d6, __uint_as_float(u6 << 16), ax);
                ay = fmaf(d6, __uint_as_float(u6 & 0xffff0000u), ay);
                bx = fmaf(d7, __uint_as_float(u7 << 16), bx);
                by = fmaf(d7, __uint_as_float(u7 & 0xffff0000u), by);
            }
        }
        for (; j + 3 < end; j += 4) {
            int s0 = ebuf[j], s1 = ebuf[j + 1], s2 = ebuf[j + 2], s3 = ebuf[j + 3];
            float d0 = dinv[s0], d1 = dinv[s1], d2 = dinv[s2], d3 = dinv[s3];
            unsigned int u0 = hl[(unsigned)s0 << 6];
            unsigned int u1 = hl[(unsigned)s1 << 6];
            unsigned int u2 = hl[(unsigned)s2 << 6];
            unsigned int u3 = hl[(unsigned)s3 << 6];
            ax = fmaf(d0, __uint_as_float(u0 << 16), ax);
            ay = fmaf(d0, __uint_as_float(u0 & 0xffff0000u), ay);
            bx = fmaf(d1, __uint_as_float(u1 << 16), bx);
            by = fmaf(d1, __uint_as_float(u1 & 0xffff0000u), by);
            ax = fmaf(d2, __uint_as_float(u2 << 16), ax);
            ay = fmaf(d2, __uint_as_float(u2 & 0xffff0000u), ay);
            bx = fmaf(d3, __uint_as_float(u3 << 16), bx);
            by = fmaf(d3, __uint_as_float(u3 & 0xffff0000u), by);
        }
        for (; j < end; ++j) {
            int s0 = ebuf[j];
            float d0 = dinv[s0];
            unsigned int u0 = hl[(unsigned)s0 << 6];
            ax = fmaf(d0, __uint_as_float(u0 << 16), ax);
            ay = fmaf(d0, __uint_as_float(u0 & 0xffff0000u), ay);
        }
        ax += bx;
        ay += by;

        float2 r = make_float2(fmaf(ax, di, bb.x), fmaf(ay, di, bb.y));
        ((float2*)(out + (size_t)i * FDIM))[lane] = r;
    }
}

extern "C" void kernel_launch(void* const* d_in, const int* in_sizes, int n_in,
                              void* d_out, int out_size, void* d_ws, size_t ws_size,
                              hipStream_t stream) {
    const float* x  = (const float*)d_in[0];
    const int*   ei = (const int*)d_in[1];     // [2, E] int32
    const float* W  = (const float*)d_in[2];
    const float* b  = (const float*)d_in[3];

    int n = in_sizes[0] / FDIM;
    int e = in_sizes[1] / 2;
    const int* src = ei;
    const int* dst = ei + e;
    float* out = (float*)d_out;

    int nb = (n + 255) >> 8;               // node buckets
    int nchunks = (e + EPB - 1) / EPB;     // edge chunks
    int ntiles = (n + 63) / 64;            // gemm row tiles

    char* ws = (char*)d_ws;
    size_t off = 0;
    auto alloc = [&](size_t bytes) {
        char* p = ws + off;
        off += (bytes + 511) & ~(size_t)511;
        return p;
    };
    float*          dinv      = (float*)alloc((size_t)n * 4);
    int*            row_start = (int*)alloc((size_t)(n + 1) * 4);
    int*            bcnt      = (int*)alloc((size_t)NBMAX * CPAD * 4);  // padded; adjacent:
    int*            gcur      = (int*)alloc((size_t)NBMAX * CPAD * 4);  // one memset covers
    int*            gtick     = (int*)alloc(512);                       // bcnt+gcur+gtick
    unsigned short* whi       = (unsigned short*)alloc((size_t)FDIM * FDIM * 2);
    unsigned int*   coarse    = (unsigned int*)alloc((size_t)e * 4);
    int*            ebuf      = (int*)alloc((size_t)e * 4);
    unsigned short* hs        = (unsigned short*)alloc((size_t)n * FDIM * 2);

    hipMemsetAsync(bcnt, 0, (size_t)NBMAX * CPAD * 4 * 2 + 512, stream);  // bcnt+gcur+gtick

    {
        void* args[] = {
            (void*)&src, (void*)&dst, (void*)&bcnt, (void*)&gcur, (void*)&gtick,
            (void*)&coarse, (void*)&x, (void*)&W, (void*)&whi, (void*)&hs,
            (void*)&dinv, (void*)&row_start, (void*)&ebuf,
            (void*)&e, (void*)&n, (void*)&nchunks, (void*)&nb, (void*)&ntiles};
        hipLaunchCooperativeKernel((const void*)k_fused, dim3(NBLK), dim3(256), args, 0, stream);
    }
    {
        int blocks = (n + 3) / 4;
        if (blocks > 2048) blocks = 2048;
        k_gather<<<blocks, 256, 0, stream>>>(hs, ebuf, row_start, dinv, b, out, n);
    }
}